// Round 1
// baseline (796.952 us; speedup 1.0000x reference)
//
#include <hip/hip_runtime.h>

// ---------------------------------------------------------------------------
// BasicTransDecoderBlock on MI355X — fp32 baseline, flash attention w/ K-split
// ---------------------------------------------------------------------------
static constexpr float SCALE = 0.17677669529663687f; // 32^-0.5
static constexpr float L2E   = 1.4426950408889634f;

// ---- block reduce (sum, sumsq) for 256-thread blocks ----------------------
__device__ inline void bred2(float& s, float& ss) {
  #pragma unroll
  for (int off = 32; off; off >>= 1) {
    s  += __shfl_down(s, off, 64);
    ss += __shfl_down(ss, off, 64);
  }
  __shared__ float as_[4], ass_[4];
  int wid = threadIdx.x >> 6;
  if ((threadIdx.x & 63) == 0) { as_[wid] = s; ass_[wid] = ss; }
  __syncthreads();
  s  = as_[0] + as_[1] + as_[2] + as_[3];
  ss = ass_[0] + ass_[1] + ass_[2] + ass_[3];
}

// ---- training-mode BatchNorm3d (biased var), optional ReLU ----------------
template<bool RELU>
__global__ __launch_bounds__(256) void bn_kernel(
    const float* __restrict__ in, float* __restrict__ out,
    const float* __restrict__ gamma, const float* __restrict__ beta, int S) {
  int c = blockIdx.x;
  const float* src = in + (size_t)c * S;
  float s = 0.f, ss = 0.f;
  for (int i = threadIdx.x; i < S; i += 256) { float v = src[i]; s += v; ss = fmaf(v, v, ss); }
  bred2(s, ss);
  float inv = 1.0f / (float)S;
  float m   = s * inv;
  float var = ss * inv - m * m;
  float rs  = rsqrtf(var + 1e-5f);
  float a   = gamma[c] * rs;
  float b   = beta[c] - m * a;
  float* dst = out + (size_t)c * S;
  for (int i = threadIdx.x; i < S; i += 256) {
    float v = fmaf(src[i], a, b);
    if (RELU) v = fmaxf(v, 0.f);
    dst[i] = v;
  }
}

// ---- pointwise conv: out[oc,s] = bias[oc] + addend[oc,s] + sum_ic w[oc,ic]*in[ic,s]
__global__ __launch_bounds__(256) void pw_kernel(
    const float* __restrict__ in, const float* __restrict__ w,
    const float* __restrict__ bias_oc, const float* __restrict__ addend,
    float* __restrict__ out, int IC, int S) {
  int t = blockIdx.x * 256 + threadIdx.x;
  int oc = t / S, s = t - oc * S;
  float acc = bias_oc ? bias_oc[oc] : 0.f;
  if (addend) acc += addend[t];
  const float* wr = w + (size_t)oc * IC;
  const float* ip = in + s;
  #pragma unroll 4
  for (int ic = 0; ic < IC; ic++) acc = fmaf(wr[ic], ip[(size_t)ic * S], acc);
  out[t] = acc;
}

// ---- depthwise 3x3x3, pad=1, cube side n ----------------------------------
__global__ __launch_bounds__(256) void dw_kernel(
    const float* __restrict__ in, const float* __restrict__ w,
    float* __restrict__ out, int n, int nn, int n3) {
  int t = blockIdx.x * 256 + threadIdx.x;
  int c = t / n3, s = t - c * n3;
  int z = s / nn, r = s - z * nn, y = r / n, x = r - y * n;
  const float* src = in + (size_t)c * n3;
  const float* wc  = w + c * 27;
  float acc = 0.f;
  #pragma unroll
  for (int kd = 0; kd < 3; kd++) {
    int zz = z + kd - 1;
    if (zz < 0 || zz >= n) continue;
    #pragma unroll
    for (int kh = 0; kh < 3; kh++) {
      int yy = y + kh - 1;
      if (yy < 0 || yy >= n) continue;
      #pragma unroll
      for (int kw = 0; kw < 3; kw++) {
        int xx = x + kw - 1;
        if (xx < 0 || xx >= n) continue;
        acc = fmaf(src[(zz * n + yy) * n + xx], wc[kd * 9 + kh * 3 + kw], acc);
      }
    }
  }
  out[t] = acc;
}

// ---- align_corners trilinear coefficients, 8 -> 16 ------------------------
__device__ inline void icoef8(int o, int& lo, int& hi, float& w) {
  float p = (float)o * (7.0f / 15.0f);
  int l = (int)floorf(p);
  if (l > 7) l = 7;
  int h = l + 1 > 7 ? 7 : l + 1;
  w  = p - (float)l;
  lo = l; hi = h;
}

__device__ inline float trilin8(const float* __restrict__ p,
                                int z0, int z1, float wz,
                                int y0, int y1, float wy,
                                int x0, int x1, float wx) {
  float c00 = p[(z0*8+y0)*8+x0]*(1.f-wx) + p[(z0*8+y0)*8+x1]*wx;
  float c01 = p[(z0*8+y1)*8+x0]*(1.f-wx) + p[(z0*8+y1)*8+x1]*wx;
  float c10 = p[(z1*8+y0)*8+x0]*(1.f-wx) + p[(z1*8+y0)*8+x1]*wx;
  float c11 = p[(z1*8+y1)*8+x0]*(1.f-wx) + p[(z1*8+y1)*8+x1]*wx;
  float c0 = c00*(1.f-wy) + c01*wy;
  float c1 = c10*(1.f-wy) + c11*wy;
  return c0*(1.f-wz) + c1*wz;
}

// residue: 128ch 8^3 -> 16^3
__global__ __launch_bounds__(256) void interp_res_kernel(
    const float* __restrict__ src, float* __restrict__ out) {
  int t = blockIdx.x * 256 + threadIdx.x;   // 524288
  int s = t & 4095, c = t >> 12;
  int z = s >> 8, y = (s >> 4) & 15, x = s & 15;
  int z0,z1,y0,y1,x0,x1; float wz,wy,wx;
  icoef8(z, z0, z1, wz); icoef8(y, y0, y1, wy); icoef8(x, x0, x1, wx);
  out[t] = trilin8(src + c * 512, z0, z1, wz, y0, y1, wy, x0, x1, wx);
}

// k/v: 8^3 -> 16^3 with head-split layout [head][j][dh]
__global__ __launch_bounds__(256) void interp_kv_kernel(
    const float* __restrict__ kv8, float* __restrict__ k16, float* __restrict__ v16) {
  int t = blockIdx.x * 256 + threadIdx.x;   // 1,048,576
  int dh    = t & 31;
  int j     = (t >> 5) & 4095;
  int head  = (t >> 17) & 3;
  int which = t >> 19;                       // 0 = k, 1 = v
  int c  = dh * 4 + head;                    // channel -> (dim_head, heads) layout
  int sc = which * 128 + c;                  // kv8 channel
  int z = j >> 8, y = (j >> 4) & 15, x = j & 15;
  int z0,z1,y0,y1,x0,x1; float wz,wy,wx;
  icoef8(z, z0, z1, wz); icoef8(y, y0, y1, wy); icoef8(x, x0, x1, wx);
  float val = trilin8(kv8 + (size_t)sc * 512, z0, z1, wz, y0, y1, wy, x0, x1, wx);
  float* dst = which ? v16 : k16;
  dst[(size_t)((head << 12) + j) * 32 + dh] = val;
}

// ---- flash attention, one lane = one query, key dim split 8-way -----------
__global__ __launch_bounds__(256) void attn_kernel(
    const float* __restrict__ qb, const float* __restrict__ k16,
    const float* __restrict__ v16, const float* __restrict__ table,
    float* __restrict__ part_o, float* __restrict__ part_m, float* __restrict__ part_l) {
  int gw   = (blockIdx.x * 256 + threadIdx.x) >> 6;  // wave id 0..2047
  int lane = threadIdx.x & 63;
  int head = gw >> 9;
  int rem  = gw & 511;
  int i    = (rem >> 3) * 64 + lane;                 // query index
  int ks   = rem & 7;                                // key split

  float qr[32];
  #pragma unroll
  for (int d = 0; d < 32; d++) qr[d] = qb[(d * 4 + head) * 4096 + i];
  int iz = i >> 8, iy = (i >> 4) & 15, ix = i & 15;

  float m = -1e30f, l = 0.f, o[32];
  #pragma unroll
  for (int d = 0; d < 32; d++) o[d] = 0.f;

  int jbase = ks << 9;
  const float* khd = k16 + (size_t)(head << 12) * 32;
  const float* vhd = v16 + (size_t)(head << 12) * 32;

  for (int jc = 0; jc < 512; jc += 8) {
    float bias[8], s[8];
    #pragma unroll
    for (int jj = 0; jj < 8; jj++) {
      int j = jbase + jc + jj;
      int dz = iz - (j >> 8), dy = iy - ((j >> 4) & 15), dx = ix - (j & 15);
      int idx = (dz + 15) * 31 + (dy + 15) + dx;     // mod wrap for negatives
      if (idx < 0) idx += 29791;
      bias[jj] = table[idx * 4 + head];
    }
    #pragma unroll
    for (int jj = 0; jj < 8; jj++) {
      int j = jbase + jc + jj;
      const float4* kr = (const float4*)(khd + (size_t)j * 32);
      float acc = 0.f;
      #pragma unroll
      for (int g = 0; g < 8; g++) {
        float4 kk = kr[g];
        acc = fmaf(qr[4*g+0], kk.x, acc);
        acc = fmaf(qr[4*g+1], kk.y, acc);
        acc = fmaf(qr[4*g+2], kk.z, acc);
        acc = fmaf(qr[4*g+3], kk.w, acc);
      }
      s[jj] = (acc + bias[jj]) * SCALE;
    }
    float cm = s[0];
    #pragma unroll
    for (int jj = 1; jj < 8; jj++) cm = fmaxf(cm, s[jj]);
    float mn = fmaxf(m, cm);
    float corr = exp2f((m - mn) * L2E);
    m = mn;
    l *= corr;
    #pragma unroll
    for (int d = 0; d < 32; d++) o[d] *= corr;
    #pragma unroll
    for (int jj = 0; jj < 8; jj++) {
      float p = exp2f((s[jj] - m) * L2E);
      l += p;
      const float4* vr = (const float4*)(vhd + (size_t)(jbase + jc + jj) * 32);
      #pragma unroll
      for (int g = 0; g < 8; g++) {
        float4 vv = vr[g];
        o[4*g+0] = fmaf(p, vv.x, o[4*g+0]);
        o[4*g+1] = fmaf(p, vv.y, o[4*g+1]);
        o[4*g+2] = fmaf(p, vv.z, o[4*g+2]);
        o[4*g+3] = fmaf(p, vv.w, o[4*g+3]);
      }
    }
  }
  int base = head * 8 + ks;
  part_m[base * 4096 + i] = m;
  part_l[base * 4096 + i] = l;
  #pragma unroll
  for (int d = 0; d < 32; d++) part_o[(size_t)(base * 32 + d) * 4096 + i] = o[d];
}

// ---- combine K-split partials, write channel-spatial layout ---------------
__global__ __launch_bounds__(256) void attn_reduce_kernel(
    const float* __restrict__ part_o, const float* __restrict__ part_m,
    const float* __restrict__ part_l, float* __restrict__ o_sp) {
  int t = blockIdx.x * 256 + threadIdx.x;  // 16384
  int i = t & 4095, head = t >> 12;
  float mk[8], mx = -1e30f;
  #pragma unroll
  for (int ks = 0; ks < 8; ks++) { mk[ks] = part_m[(head*8+ks)*4096 + i]; mx = fmaxf(mx, mk[ks]); }
  float c[8], L = 0.f;
  #pragma unroll
  for (int ks = 0; ks < 8; ks++) {
    c[ks] = exp2f((mk[ks] - mx) * L2E);
    L = fmaf(c[ks], part_l[(head*8+ks)*4096 + i], L);
  }
  float invL = 1.f / L;
  #pragma unroll
  for (int d = 0; d < 32; d++) {
    float acc = 0.f;
    #pragma unroll
    for (int ks = 0; ks < 8; ks++)
      acc = fmaf(c[ks], part_o[(size_t)((head*8+ks)*32 + d) * 4096 + i], acc);
    o_sp[(d * 4 + head) * 4096 + i] = acc * invL;
  }
}

// ---------------------------------------------------------------------------
extern "C" void kernel_launch(void* const* d_in, const int* in_sizes, int n_in,
                              void* d_out, int out_size, void* d_ws, size_t ws_size,
                              hipStream_t stream) {
  (void)in_sizes; (void)n_in; (void)out_size; (void)ws_size;
  const float* x1      = (const float*)d_in[0];
  const float* x2      = (const float*)d_in[1];
  const float* w_ch    = (const float*)d_in[2];
  const float* b_ch    = (const float*)d_in[3];
  const float* gamma_l = (const float*)d_in[4];
  const float* beta_l  = (const float*)d_in[5];
  const float* gamma_h = (const float*)d_in[6];
  const float* beta_h  = (const float*)d_in[7];
  const float* gamma2  = (const float*)d_in[8];
  const float* beta2   = (const float*)d_in[9];
  const float* kv_dw   = (const float*)d_in[10];
  const float* kv_pw   = (const float*)d_in[11];
  const float* q_dw    = (const float*)d_in[12];
  const float* q_pw    = (const float*)d_in[13];
  const float* out_dw  = (const float*)d_in[14];
  const float* out_pw  = (const float*)d_in[15];
  const float* w_mlp   = (const float*)d_in[16];
  const float* rtab    = (const float*)d_in[17];

  float* ws = (float*)d_ws;
  // early scratch (dead before attention) — aliased by attention partials
  float* x1n  = ws + 0;        // 131072
  float* x2n  = ws + 131072;   // 524288
  float* res8 = ws + 655360;   // 65536
  float* kvdw = ws + 720896;   // 131072
  float* kv8  = ws + 851968;   // 131072
  float* qdw  = ws + 983040;   // 524288  (ends 1507328)
  float* part_o = ws + 0;        // 4194304 (aliases all of the above)
  float* part_m = ws + 4194304;  // 131072
  float* part_l = ws + 4325376;  // 131072  (ends 4456448)
  const size_t B = 4456448;
  float* qb   = ws + B;
  float* k16  = ws + B +  524288;
  float* v16  = ws + B + 1048576;
  float* r16  = ws + B + 1572864;
  float* o_sp = ws + B + 2097152;
  float* odw  = ws + B + 2621440;
  float* res2 = ws + B + 3145728;
  float* ybuf = ws + B + 3670016;  // ends B + 4194304 (~34.6 MB total)

  bn_kernel<false><<<256, 256, 0, stream>>>(x1, x1n, gamma_l, beta_l, 512);
  bn_kernel<false><<<128, 256, 0, stream>>>(x2, x2n, gamma_h, beta_h, 4096);
  // residue path: pointwise 256->128 (+bias) at 8^3 on RAW x1, then upsample
  pw_kernel<<<256, 256, 0, stream>>>(x1, w_ch, b_ch, nullptr, res8, 256, 512);
  // kv = dwsep(x1n): dw 3^3 then pw 256->256
  dw_kernel<<<512, 256, 0, stream>>>(x1n, kv_dw, kvdw, 8, 64, 512);
  pw_kernel<<<512, 256, 0, stream>>>(kvdw, kv_pw, nullptr, nullptr, kv8, 256, 512);
  // q = dwsep(x2n): dw 3^3 then pw 128->128 (spatial layout)
  dw_kernel<<<2048, 256, 0, stream>>>(x2n, q_dw, qdw, 16, 256, 4096);
  pw_kernel<<<2048, 256, 0, stream>>>(qdw, q_pw, nullptr, nullptr, qb, 128, 4096);
  interp_res_kernel<<<2048, 256, 0, stream>>>(res8, r16);
  interp_kv_kernel<<<4096, 256, 0, stream>>>(kv8, k16, v16);
  // flash attention with rel-bias, 8-way K split
  attn_kernel<<<512, 256, 0, stream>>>(qb, k16, v16, rtab, part_o, part_m, part_l);
  attn_reduce_kernel<<<64, 256, 0, stream>>>(part_o, part_m, part_l, o_sp);
  // out projection: dwsep + residue
  dw_kernel<<<2048, 256, 0, stream>>>(o_sp, out_dw, odw, 16, 256, 4096);
  pw_kernel<<<2048, 256, 0, stream>>>(odw, out_pw, nullptr, r16, res2, 128, 4096);
  // mlp: relu(bn(res2)) -> pointwise + res2
  bn_kernel<true><<<128, 256, 0, stream>>>(res2, ybuf, gamma2, beta2, 4096);
  pw_kernel<<<2048, 256, 0, stream>>>(ybuf, w_mlp, nullptr, res2, (float*)d_out, 128, 4096);
}

// Round 2
// 694.177 us; speedup vs baseline: 1.1481x; 1.1481x over previous
//
#include <hip/hip_runtime.h>

// ---------------------------------------------------------------------------
// BasicTransDecoderBlock on MI355X — fp32, flash attention w/ LDS bias LUT,
// 32-way key split (8 blocks x 4 waves), in-block LDS partial combine.
// ---------------------------------------------------------------------------
static constexpr float SCALE = 0.17677669529663687f; // 32^-0.5
static constexpr float L2E   = 1.4426950408889634f;

// ---- block reduce (sum, sumsq) for 256-thread blocks ----------------------
__device__ inline void bred2(float& s, float& ss) {
  #pragma unroll
  for (int off = 32; off; off >>= 1) {
    s  += __shfl_down(s, off, 64);
    ss += __shfl_down(ss, off, 64);
  }
  __shared__ float as_[4], ass_[4];
  int wid = threadIdx.x >> 6;
  if ((threadIdx.x & 63) == 0) { as_[wid] = s; ass_[wid] = ss; }
  __syncthreads();
  s  = as_[0] + as_[1] + as_[2] + as_[3];
  ss = ass_[0] + ass_[1] + ass_[2] + ass_[3];
}

// ---- training-mode BatchNorm3d (biased var), optional ReLU ----------------
template<bool RELU>
__global__ __launch_bounds__(256) void bn_kernel(
    const float* __restrict__ in, float* __restrict__ out,
    const float* __restrict__ gamma, const float* __restrict__ beta, int S) {
  int c = blockIdx.x;
  const float* src = in + (size_t)c * S;
  float s = 0.f, ss = 0.f;
  for (int i = threadIdx.x; i < S; i += 256) { float v = src[i]; s += v; ss = fmaf(v, v, ss); }
  bred2(s, ss);
  float inv = 1.0f / (float)S;
  float m   = s * inv;
  float var = ss * inv - m * m;
  float rs  = rsqrtf(var + 1e-5f);
  float a   = gamma[c] * rs;
  float b   = beta[c] - m * a;
  float* dst = out + (size_t)c * S;
  for (int i = threadIdx.x; i < S; i += 256) {
    float v = fmaf(src[i], a, b);
    if (RELU) v = fmaxf(v, 0.f);
    dst[i] = v;
  }
}

// ---- pointwise conv, one oc per block-row, VEC outputs per thread ---------
// out[oc,s] = bias[oc] + addend[oc,s] + sum_ic w[oc,ic]*in[ic,s]
template<int VEC>
__global__ __launch_bounds__(256) void pw2_kernel(
    const float* __restrict__ in, const float* __restrict__ w,
    const float* __restrict__ bias_oc, const float* __restrict__ addend,
    float* __restrict__ out, int IC, int S, int nsb) {
  int oc = blockIdx.x / nsb;
  int sb = blockIdx.x - oc * nsb;
  int s0 = (sb * 256 + threadIdx.x) * VEC;
  float acc[VEC];
  float b0 = bias_oc ? bias_oc[oc] : 0.f;
  #pragma unroll
  for (int v = 0; v < VEC; v++) acc[v] = b0;
  size_t obase = (size_t)oc * S + s0;
  if (addend) {
    #pragma unroll
    for (int v = 0; v < VEC; v++) acc[v] += addend[obase + v];
  }
  const float* wr = w + (size_t)oc * IC;
  const float* ip = in + s0;
  #pragma unroll 4
  for (int ic = 0; ic < IC; ic++) {
    float wv = wr[ic];
    const float* p = ip + (size_t)ic * S;
    #pragma unroll
    for (int v = 0; v < VEC; v++) acc[v] = fmaf(wv, p[v], acc[v]);
  }
  #pragma unroll
  for (int v = 0; v < VEC; v++) out[obase + v] = acc[v];
}

// ---- depthwise 3x3x3, pad=1, cube side n ----------------------------------
__global__ __launch_bounds__(256) void dw_kernel(
    const float* __restrict__ in, const float* __restrict__ w,
    float* __restrict__ out, int n, int nn, int n3) {
  int t = blockIdx.x * 256 + threadIdx.x;
  int c = t / n3, s = t - c * n3;
  int z = s / nn, r = s - z * nn, y = r / n, x = r - y * n;
  const float* src = in + (size_t)c * n3;
  const float* wc  = w + c * 27;
  float acc = 0.f;
  #pragma unroll
  for (int kd = 0; kd < 3; kd++) {
    int zz = z + kd - 1;
    if (zz < 0 || zz >= n) continue;
    #pragma unroll
    for (int kh = 0; kh < 3; kh++) {
      int yy = y + kh - 1;
      if (yy < 0 || yy >= n) continue;
      #pragma unroll
      for (int kw = 0; kw < 3; kw++) {
        int xx = x + kw - 1;
        if (xx < 0 || xx >= n) continue;
        acc = fmaf(src[(zz * n + yy) * n + xx], wc[kd * 9 + kh * 3 + kw], acc);
      }
    }
  }
  out[t] = acc;
}

// ---- align_corners trilinear coefficients, 8 -> 16 ------------------------
__device__ inline void icoef8(int o, int& lo, int& hi, float& w) {
  float p = (float)o * (7.0f / 15.0f);
  int l = (int)floorf(p);
  if (l > 7) l = 7;
  int h = l + 1 > 7 ? 7 : l + 1;
  w  = p - (float)l;
  lo = l; hi = h;
}

__device__ inline float trilin8(const float* __restrict__ p,
                                int z0, int z1, float wz,
                                int y0, int y1, float wy,
                                int x0, int x1, float wx) {
  float c00 = p[(z0*8+y0)*8+x0]*(1.f-wx) + p[(z0*8+y0)*8+x1]*wx;
  float c01 = p[(z0*8+y1)*8+x0]*(1.f-wx) + p[(z0*8+y1)*8+x1]*wx;
  float c10 = p[(z1*8+y0)*8+x0]*(1.f-wx) + p[(z1*8+y0)*8+x1]*wx;
  float c11 = p[(z1*8+y1)*8+x0]*(1.f-wx) + p[(z1*8+y1)*8+x1]*wx;
  float c0 = c00*(1.f-wy) + c01*wy;
  float c1 = c10*(1.f-wy) + c11*wy;
  return c0*(1.f-wz) + c1*wz;
}

// residue: 128ch 8^3 -> 16^3
__global__ __launch_bounds__(256) void interp_res_kernel(
    const float* __restrict__ src, float* __restrict__ out) {
  int t = blockIdx.x * 256 + threadIdx.x;   // 524288
  int s = t & 4095, c = t >> 12;
  int z = s >> 8, y = (s >> 4) & 15, x = s & 15;
  int z0,z1,y0,y1,x0,x1; float wz,wy,wx;
  icoef8(z, z0, z1, wz); icoef8(y, y0, y1, wy); icoef8(x, x0, x1, wx);
  out[t] = trilin8(src + c * 512, z0, z1, wz, y0, y1, wy, x0, x1, wx);
}

// k/v: 8^3 -> 16^3 with head-split layout [head][j][dh]
__global__ __launch_bounds__(256) void interp_kv_kernel(
    const float* __restrict__ kv8, float* __restrict__ k16, float* __restrict__ v16) {
  int t = blockIdx.x * 256 + threadIdx.x;   // 1,048,576
  int dh    = t & 31;
  int j     = (t >> 5) & 4095;
  int head  = (t >> 17) & 3;
  int which = t >> 19;                       // 0 = k, 1 = v
  int c  = dh * 4 + head;                    // channel -> (dim_head, heads) layout
  int sc = which * 128 + c;                  // kv8 channel
  int z = j >> 8, y = (j >> 4) & 15, x = j & 15;
  int z0,z1,y0,y1,x0,x1; float wz,wy,wx;
  icoef8(z, z0, z1, wz); icoef8(y, y0, y1, wy); icoef8(x, x0, x1, wx);
  float val = trilin8(kv8 + (size_t)sc * 512, z0, z1, wz, y0, y1, wy, x0, x1, wx);
  float* dst = which ? v16 : k16;
  dst[(size_t)((head << 12) + j) * 32 + dh] = val;
}

// ---- flash attention --------------------------------------------------------
// grid: 4 heads x 64 qtiles x 8 ksplit-blocks = 2048 blocks, 4 waves/block.
// Each wave: 64 queries (one per lane) x 128 keys. Waves combine in LDS,
// block writes one 8-way partial (m, l, o) for attn_reduce_kernel.
__global__ __launch_bounds__(256, 4) void attn_kernel(
    const float* __restrict__ qb, const float* __restrict__ k16,
    const float* __restrict__ v16, const float* __restrict__ table,
    float* __restrict__ part_o, float* __restrict__ part_m, float* __restrict__ part_l) {
  __shared__ float smem[8960];               // lut(992) aliases red_o(8448)
  float* lut   = smem;                       // [991]
  float* red_o = smem;                       // [4][64][33]
  float* red_m = smem + 8448;                // [4][64]
  float* red_l = smem + 8704;                // [4][64]

  int head = blockIdx.x >> 9;
  int rem  = blockIdx.x & 511;
  int qt   = rem >> 3;
  int ksb  = rem & 7;
  int wid  = threadIdx.x >> 6;
  int lane = threadIdx.x & 63;
  int i    = qt * 64 + lane;                 // query index

  // stage bias LUT: logical idx l in [-15, 975] -> lut[l+15]
  for (int u = threadIdx.x; u < 991; u += 256) {
    int p = (u < 15) ? (u - 15 + 29791) : (u - 15);
    lut[u] = table[p * 4 + head];
  }
  __syncthreads();

  float qr[32];
  #pragma unroll
  for (int d = 0; d < 32; d++) qr[d] = qb[(d * 4 + head) * 4096 + i];
  int iz = i >> 8, iy = (i >> 4) & 15, ix = i & 15;
  int lanebase = iz * 31 + iy + ix;          // per-lane constant part of lut idx

  float m = -1e30f, l = 0.f, o[32];
  #pragma unroll
  for (int d = 0; d < 32; d++) o[d] = 0.f;

  int ks    = ksb * 4 + wid;                 // 0..31
  int jbase = ks * 128;
  const float* khd = k16 + (size_t)(head << 12) * 32;
  const float* vhd = v16 + (size_t)(head << 12) * 32;

  for (int jc = 0; jc < 128; jc += 8) {
    float s[8];
    #pragma unroll
    for (int jj = 0; jj < 8; jj++) {
      int j = jbase + jc + jj;
      int joff = (15 - (j >> 8)) * 31 + (15 - ((j >> 4) & 15)) + (15 - (j & 15));
      float bias = lut[lanebase + joff];
      const float4* kr = (const float4*)(khd + (size_t)j * 32);
      float acc = 0.f;
      #pragma unroll
      for (int g = 0; g < 8; g++) {
        float4 kk = kr[g];
        acc = fmaf(qr[4*g+0], kk.x, acc);
        acc = fmaf(qr[4*g+1], kk.y, acc);
        acc = fmaf(qr[4*g+2], kk.z, acc);
        acc = fmaf(qr[4*g+3], kk.w, acc);
      }
      s[jj] = (acc + bias) * SCALE;
    }
    float cm = s[0];
    #pragma unroll
    for (int jj = 1; jj < 8; jj++) cm = fmaxf(cm, s[jj]);
    float mn = fmaxf(m, cm);
    float corr = exp2f((m - mn) * L2E);
    m = mn;
    l *= corr;
    #pragma unroll
    for (int d = 0; d < 32; d++) o[d] *= corr;
    #pragma unroll
    for (int jj = 0; jj < 8; jj++) {
      float p = exp2f((s[jj] - m) * L2E);
      l += p;
      const float4* vr = (const float4*)(vhd + (size_t)(jbase + jc + jj) * 32);
      #pragma unroll
      for (int g = 0; g < 8; g++) {
        float4 vv = vr[g];
        o[4*g+0] = fmaf(p, vv.x, o[4*g+0]);
        o[4*g+1] = fmaf(p, vv.y, o[4*g+1]);
        o[4*g+2] = fmaf(p, vv.z, o[4*g+2]);
        o[4*g+3] = fmaf(p, vv.w, o[4*g+3]);
      }
    }
  }

  // per-wave partials -> LDS (lut region is dead now; barrier orders reuse)
  __syncthreads();
  {
    int base = (wid * 64 + lane) * 33;
    #pragma unroll
    for (int d = 0; d < 32; d++) red_o[base + d] = o[d];
    red_m[wid * 64 + lane] = m;
    red_l[wid * 64 + lane] = l;
  }
  __syncthreads();

  // combine 4 waves -> one 8-way partial. thread t: q = t>>2, 8 d's each.
  int q  = threadIdx.x >> 2;
  int dg = threadIdx.x & 3;
  float m0 = red_m[q], m1 = red_m[64 + q], m2 = red_m[128 + q], m3 = red_m[192 + q];
  float mx = fmaxf(fmaxf(m0, m1), fmaxf(m2, m3));
  float c0 = exp2f((m0 - mx) * L2E);
  float c1 = exp2f((m1 - mx) * L2E);
  float c2 = exp2f((m2 - mx) * L2E);
  float c3 = exp2f((m3 - mx) * L2E);
  float L = c0 * red_l[q] + c1 * red_l[64 + q] + c2 * red_l[128 + q] + c3 * red_l[192 + q];
  int i2   = qt * 64 + q;
  int base = head * 8 + ksb;
  if (dg == 0) {
    part_m[base * 4096 + i2] = mx;
    part_l[base * 4096 + i2] = L;
  }
  #pragma unroll
  for (int k = 0; k < 8; k++) {
    int d = dg * 8 + k;
    float acc = c0 * red_o[q * 33 + d] + c1 * red_o[(64 + q) * 33 + d]
              + c2 * red_o[(128 + q) * 33 + d] + c3 * red_o[(192 + q) * 33 + d];
    part_o[(size_t)(base * 32 + d) * 4096 + i2] = acc;
  }
}

// ---- combine K-split partials, write channel-spatial layout ---------------
__global__ __launch_bounds__(256) void attn_reduce_kernel(
    const float* __restrict__ part_o, const float* __restrict__ part_m,
    const float* __restrict__ part_l, float* __restrict__ o_sp) {
  int t = blockIdx.x * 256 + threadIdx.x;  // 16384
  int i = t & 4095, head = t >> 12;
  float mk[8], mx = -1e30f;
  #pragma unroll
  for (int ks = 0; ks < 8; ks++) { mk[ks] = part_m[(head*8+ks)*4096 + i]; mx = fmaxf(mx, mk[ks]); }
  float c[8], L = 0.f;
  #pragma unroll
  for (int ks = 0; ks < 8; ks++) {
    c[ks] = exp2f((mk[ks] - mx) * L2E);
    L = fmaf(c[ks], part_l[(head*8+ks)*4096 + i], L);
  }
  float invL = 1.f / L;
  #pragma unroll
  for (int d = 0; d < 32; d++) {
    float acc = 0.f;
    #pragma unroll
    for (int ks = 0; ks < 8; ks++)
      acc = fmaf(c[ks], part_o[(size_t)((head*8+ks)*32 + d) * 4096 + i], acc);
    o_sp[(d * 4 + head) * 4096 + i] = acc * invL;
  }
}

// ---------------------------------------------------------------------------
extern "C" void kernel_launch(void* const* d_in, const int* in_sizes, int n_in,
                              void* d_out, int out_size, void* d_ws, size_t ws_size,
                              hipStream_t stream) {
  (void)in_sizes; (void)n_in; (void)out_size; (void)ws_size;
  const float* x1      = (const float*)d_in[0];
  const float* x2      = (const float*)d_in[1];
  const float* w_ch    = (const float*)d_in[2];
  const float* b_ch    = (const float*)d_in[3];
  const float* gamma_l = (const float*)d_in[4];
  const float* beta_l  = (const float*)d_in[5];
  const float* gamma_h = (const float*)d_in[6];
  const float* beta_h  = (const float*)d_in[7];
  const float* gamma2  = (const float*)d_in[8];
  const float* beta2   = (const float*)d_in[9];
  const float* kv_dw   = (const float*)d_in[10];
  const float* kv_pw   = (const float*)d_in[11];
  const float* q_dw    = (const float*)d_in[12];
  const float* q_pw    = (const float*)d_in[13];
  const float* out_dw  = (const float*)d_in[14];
  const float* out_pw  = (const float*)d_in[15];
  const float* w_mlp   = (const float*)d_in[16];
  const float* rtab    = (const float*)d_in[17];

  float* ws = (float*)d_ws;
  // early scratch (dead before attention) — aliased by attention partials
  float* x1n  = ws + 0;        // 131072
  float* x2n  = ws + 131072;   // 524288
  float* res8 = ws + 655360;   // 65536
  float* kvdw = ws + 720896;   // 131072
  float* kv8  = ws + 851968;   // 131072
  float* qdw  = ws + 983040;   // 524288  (ends 1507328)
  float* part_o = ws + 0;        // 4194304 (aliases all of the above)
  float* part_m = ws + 4194304;  // 131072
  float* part_l = ws + 4325376;  // 131072  (ends 4456448)
  const size_t B = 4456448;
  float* qb   = ws + B;
  float* k16  = ws + B +  524288;
  float* v16  = ws + B + 1048576;
  float* r16  = ws + B + 1572864;
  float* o_sp = ws + B + 2097152;
  float* odw  = ws + B + 2621440;
  float* res2 = ws + B + 3145728;
  float* ybuf = ws + B + 3670016;  // ends B + 4194304 (~34.6 MB total)

  bn_kernel<false><<<256, 256, 0, stream>>>(x1, x1n, gamma_l, beta_l, 512);
  bn_kernel<false><<<128, 256, 0, stream>>>(x2, x2n, gamma_h, beta_h, 4096);
  // residue path: pointwise 256->128 (+bias) at 8^3 on RAW x1, then upsample
  pw2_kernel<2><<<128, 256, 0, stream>>>(x1, w_ch, b_ch, nullptr, res8, 256, 512, 1);
  // kv = dwsep(x1n): dw 3^3 then pw 256->256
  dw_kernel<<<512, 256, 0, stream>>>(x1n, kv_dw, kvdw, 8, 64, 512);
  pw2_kernel<2><<<256, 256, 0, stream>>>(kvdw, kv_pw, nullptr, nullptr, kv8, 256, 512, 1);
  // q = dwsep(x2n): dw 3^3 then pw 128->128 (spatial layout)
  dw_kernel<<<2048, 256, 0, stream>>>(x2n, q_dw, qdw, 16, 256, 4096);
  pw2_kernel<4><<<512, 256, 0, stream>>>(qdw, q_pw, nullptr, nullptr, qb, 128, 4096, 4);
  interp_res_kernel<<<2048, 256, 0, stream>>>(res8, r16);
  interp_kv_kernel<<<4096, 256, 0, stream>>>(kv8, k16, v16);
  // flash attention with rel-bias LUT, 32-way key split (8 blocks x 4 waves)
  attn_kernel<<<2048, 256, 0, stream>>>(qb, k16, v16, rtab, part_o, part_m, part_l);
  attn_reduce_kernel<<<64, 256, 0, stream>>>(part_o, part_m, part_l, o_sp);
  // out projection: dwsep + residue
  dw_kernel<<<2048, 256, 0, stream>>>(o_sp, out_dw, odw, 16, 256, 4096);
  pw2_kernel<4><<<512, 256, 0, stream>>>(odw, out_pw, nullptr, r16, res2, 128, 4096, 4);
  // mlp: relu(bn(res2)) -> pointwise + res2
  bn_kernel<true><<<128, 256, 0, stream>>>(res2, ybuf, gamma2, beta2, 4096);
  pw2_kernel<4><<<512, 256, 0, stream>>>(ybuf, w_mlp, nullptr, res2, (float*)d_out, 128, 4096, 4);
}

// Round 3
// 224.889 us; speedup vs baseline: 3.5438x; 3.0868x over previous
//
#include <hip/hip_runtime.h>
#include <hip/hip_bf16.h>

using f32x4  = __attribute__((ext_vector_type(4))) float;
using bf16x8 = __attribute__((ext_vector_type(8))) short;
using i32x4  = __attribute__((ext_vector_type(4))) int;

static constexpr float SCALE = 0.17677669529663687f; // 32^-0.5
static constexpr float L2E   = 1.4426950408889634f;

// ---- block reduce (sum, sumsq) for 256-thread blocks ----------------------
__device__ inline void bred2(float& s, float& ss) {
  #pragma unroll
  for (int off = 32; off; off >>= 1) {
    s  += __shfl_down(s, off, 64);
    ss += __shfl_down(ss, off, 64);
  }
  __shared__ float as_[4], ass_[4];
  int wid = threadIdx.x >> 6;
  if ((threadIdx.x & 63) == 0) { as_[wid] = s; ass_[wid] = ss; }
  __syncthreads();
  s  = as_[0] + as_[1] + as_[2] + as_[3];
  ss = ass_[0] + ass_[1] + ass_[2] + ass_[3];
}

// ---- training-mode BatchNorm3d (biased var), optional ReLU ----------------
template<bool RELU>
__global__ __launch_bounds__(256) void bn_kernel(
    const float* __restrict__ in, float* __restrict__ out,
    const float* __restrict__ gamma, const float* __restrict__ beta, int S) {
  int c = blockIdx.x;
  const float* src = in + (size_t)c * S;
  float s = 0.f, ss = 0.f;
  for (int i = threadIdx.x; i < S; i += 256) { float v = src[i]; s += v; ss = fmaf(v, v, ss); }
  bred2(s, ss);
  float inv = 1.0f / (float)S;
  float m   = s * inv;
  float var = ss * inv - m * m;
  float rs  = rsqrtf(var + 1e-5f);
  float a   = gamma[c] * rs;
  float b   = beta[c] - m * a;
  float* dst = out + (size_t)c * S;
  for (int i = threadIdx.x; i < S; i += 256) {
    float v = fmaf(src[i], a, b);
    if (RELU) v = fmaxf(v, 0.f);
    dst[i] = v;
  }
}

// ---- pointwise conv, one oc per block-row, VEC outputs per thread ---------
template<int VEC>
__global__ __launch_bounds__(256) void pw2_kernel(
    const float* __restrict__ in, const float* __restrict__ w,
    const float* __restrict__ bias_oc, const float* __restrict__ addend,
    float* __restrict__ out, int IC, int S, int nsb) {
  int oc = blockIdx.x / nsb;
  int sb = blockIdx.x - oc * nsb;
  int s0 = (sb * 256 + threadIdx.x) * VEC;
  float acc[VEC];
  float b0 = bias_oc ? bias_oc[oc] : 0.f;
  #pragma unroll
  for (int v = 0; v < VEC; v++) acc[v] = b0;
  size_t obase = (size_t)oc * S + s0;
  if (addend) {
    #pragma unroll
    for (int v = 0; v < VEC; v++) acc[v] += addend[obase + v];
  }
  const float* wr = w + (size_t)oc * IC;
  const float* ip = in + s0;
  #pragma unroll 4
  for (int ic = 0; ic < IC; ic++) {
    float wv = wr[ic];
    const float* p = ip + (size_t)ic * S;
    #pragma unroll
    for (int v = 0; v < VEC; v++) acc[v] = fmaf(wv, p[v], acc[v]);
  }
  #pragma unroll
  for (int v = 0; v < VEC; v++) out[obase + v] = acc[v];
}

// ---- depthwise 3x3x3, pad=1, cube side n ----------------------------------
__global__ __launch_bounds__(256) void dw_kernel(
    const float* __restrict__ in, const float* __restrict__ w,
    float* __restrict__ out, int n, int nn, int n3) {
  int t = blockIdx.x * 256 + threadIdx.x;
  int c = t / n3, s = t - c * n3;
  int z = s / nn, r = s - z * nn, y = r / n, x = r - y * n;
  const float* src = in + (size_t)c * n3;
  const float* wc  = w + c * 27;
  float acc = 0.f;
  #pragma unroll
  for (int kd = 0; kd < 3; kd++) {
    int zz = z + kd - 1;
    if (zz < 0 || zz >= n) continue;
    #pragma unroll
    for (int kh = 0; kh < 3; kh++) {
      int yy = y + kh - 1;
      if (yy < 0 || yy >= n) continue;
      #pragma unroll
      for (int kw = 0; kw < 3; kw++) {
        int xx = x + kw - 1;
        if (xx < 0 || xx >= n) continue;
        acc = fmaf(src[(zz * n + yy) * n + xx], wc[kd * 9 + kh * 3 + kw], acc);
      }
    }
  }
  out[t] = acc;
}

// ---- align_corners trilinear coefficients, 8 -> 16 ------------------------
__device__ inline void icoef8(int o, int& lo, int& hi, float& w) {
  float p = (float)o * (7.0f / 15.0f);
  int l = (int)floorf(p);
  if (l > 7) l = 7;
  int h = l + 1 > 7 ? 7 : l + 1;
  w  = p - (float)l;
  lo = l; hi = h;
}

__device__ inline float trilin8(const float* __restrict__ p,
                                int z0, int z1, float wz,
                                int y0, int y1, float wy,
                                int x0, int x1, float wx) {
  float c00 = p[(z0*8+y0)*8+x0]*(1.f-wx) + p[(z0*8+y0)*8+x1]*wx;
  float c01 = p[(z0*8+y1)*8+x0]*(1.f-wx) + p[(z0*8+y1)*8+x1]*wx;
  float c10 = p[(z1*8+y0)*8+x0]*(1.f-wx) + p[(z1*8+y0)*8+x1]*wx;
  float c11 = p[(z1*8+y1)*8+x0]*(1.f-wx) + p[(z1*8+y1)*8+x1]*wx;
  float c0 = c00*(1.f-wy) + c01*wy;
  float c1 = c10*(1.f-wy) + c11*wy;
  return c0*(1.f-wz) + c1*wz;
}

// residue: 128ch 8^3 -> 16^3
__global__ __launch_bounds__(256) void interp_res_kernel(
    const float* __restrict__ src, float* __restrict__ out) {
  int t = blockIdx.x * 256 + threadIdx.x;   // 524288
  int s = t & 4095, c = t >> 12;
  int z = s >> 8, y = (s >> 4) & 15, x = s & 15;
  int z0,z1,y0,y1,x0,x1; float wz,wy,wx;
  icoef8(z, z0, z1, wz); icoef8(y, y0, y1, wy); icoef8(x, x0, x1, wx);
  out[t] = trilin8(src + c * 512, z0, z1, wz, y0, y1, wy, x0, x1, wx);
}

// k/v upsample 8^3->16^3, emit bf16 in MFMA-friendly layouts:
//   Kb[head][key][dh]  (dh fastest)   Vt[head][dh][key] (key fastest)
__global__ __launch_bounds__(256) void interp_kv_kernel(
    const float* __restrict__ kv8, unsigned short* __restrict__ Kb,
    unsigned short* __restrict__ Vt) {
  int t = blockIdx.x * 256 + threadIdx.x;   // 1,048,576
  int which = t >> 19;                       // 0 = k, 1 = v
  int head  = (t >> 17) & 3;
  int dh, j;
  if (which == 0) { dh = t & 31; j = (t >> 5) & 4095; }
  else            { j = t & 4095; dh = (t >> 12) & 31; }
  int sc = which * 128 + dh * 4 + head;      // kv8 channel ((dim_head, heads) layout)
  int z = j >> 8, y = (j >> 4) & 15, x = j & 15;
  int z0,z1,y0,y1,x0,x1; float wz,wy,wx;
  icoef8(z, z0, z1, wz); icoef8(y, y0, y1, wy); icoef8(x, x0, x1, wx);
  float val = trilin8(kv8 + (size_t)sc * 512, z0, z1, wz, y0, y1, wy, x0, x1, wx);
  __hip_bfloat16 b = __float2bfloat16(val);
  unsigned short us = *reinterpret_cast<unsigned short*>(&b);
  if (which == 0) Kb[((size_t)(head << 12) + j) * 32 + dh] = us;
  else            Vt[((size_t)(head * 32) + dh) * 4096 + j] = us;
}

// ---- MFMA flash attention -------------------------------------------------
// grid 256 blocks (4 heads x 64 qtiles), 4 waves/block, wave = 16-q strip.
// S^T = mfma(Kfrag, Qfrag): lane holds 8 scores (keys) for one q.
// O^T += mfma(VTfrag, PTfrag) after in-register P->bf16 + shfl rearrange.
__device__ inline int cvtpk(float lo, float hi) {
  int r;
  asm("v_cvt_pk_bf16_f32 %0,%1,%2" : "=v"(r) : "v"(lo), "v"(hi));
  return r;
}

__global__ __launch_bounds__(256) void attn_mfma_kernel(
    const float* __restrict__ qb, const unsigned short* __restrict__ Kb,
    const unsigned short* __restrict__ Vt, const float* __restrict__ table,
    float* __restrict__ o_sp) {
  __shared__ float lut[992];
  int head = blockIdx.x >> 6;
  int qt   = blockIdx.x & 63;
  for (int u = threadIdx.x; u < 991; u += 256) {
    int p = (u < 15) ? (u - 15 + 29791) : (u - 15);
    lut[u] = table[p * 4 + head];
  }
  __syncthreads();

  int w    = threadIdx.x >> 6;
  int lane = threadIdx.x & 63;
  int qrow = lane & 15;                       // query-within-strip (= MFMA col)
  int g    = lane >> 4;                       // lane group 0..3
  int i    = (qt * 4 + w) * 16 + qrow;        // global query index
  int iz = i >> 8, iy = (i >> 4) & 15, ix = i & 15;
  int lanebase = iz * 31 + iy + ix;

  // Q B-frag: d = g*8+e, 8 strided fp32 loads -> packed bf16 (once per wave)
  float qv[8];
  #pragma unroll
  for (int e = 0; e < 8; e++) qv[e] = qb[(size_t)((g * 8 + e) * 4 + head) * 4096 + i];
  union { i32x4 i4; bf16x8 s8; } uq;
  uq.i4 = (i32x4){ cvtpk(qv[0], qv[1]), cvtpk(qv[2], qv[3]),
                   cvtpk(qv[4], qv[5]), cvtpk(qv[6], qv[7]) };
  bf16x8 qf = uq.s8;

  const unsigned short* Kh = Kb + (size_t)head * 4096 * 32;
  const unsigned short* Vh = Vt + (size_t)head * 32 * 4096;

  f32x4 zero = {0.f, 0.f, 0.f, 0.f};
  f32x4 accO0 = zero, accO1 = zero;
  float m = -1e30f, lpart = 0.f;

  // prefetch kt = 0
  bf16x8 kf0 = *(const bf16x8*)(Kh + ((size_t)(0 * 32 + 0 * 16 + qrow)) * 32 + g * 8);
  bf16x8 kf1 = *(const bf16x8*)(Kh + ((size_t)(0 * 32 + 1 * 16 + qrow)) * 32 + g * 8);
  bf16x8 vf0 = *(const bf16x8*)(Vh + (size_t)(0 + qrow)  * 4096 + 0 * 32 + g * 8);
  bf16x8 vf1 = *(const bf16x8*)(Vh + (size_t)(16 + qrow) * 4096 + 0 * 32 + g * 8);

  for (int kt = 0; kt < 128; kt++) {
    int nkt = (kt + 1) & 127;                 // last-iter wrap: harmless reload
    bf16x8 nk0 = *(const bf16x8*)(Kh + ((size_t)(nkt * 32 + qrow)) * 32 + g * 8);
    bf16x8 nk1 = *(const bf16x8*)(Kh + ((size_t)(nkt * 32 + 16 + qrow)) * 32 + g * 8);
    bf16x8 nv0 = *(const bf16x8*)(Vh + (size_t)(qrow)  * 4096 + nkt * 32 + g * 8);
    bf16x8 nv1 = *(const bf16x8*)(Vh + (size_t)(16 + qrow) * 4096 + nkt * 32 + g * 8);

    // S^T tiles: acc[reg] = score(key = kt*32 + t*16 + g*4 + reg, q)
    f32x4 accA = __builtin_amdgcn_mfma_f32_16x16x32_bf16(kf0, qf, zero, 0, 0, 0);
    f32x4 accB = __builtin_amdgcn_mfma_f32_16x16x32_bf16(kf1, qf, zero, 0, 0, 0);

    // bias: idx = lanebase + C - 4g - t - reg  (5 contiguous LDS words)
    int z0 = kt >> 3, y0 = (kt << 1) & 15;
    int Cc = 495 - 31 * z0 - y0;
    const float* lp = &lut[lanebase + Cc - 4 * g - 4];
    float l0 = lp[0], l1 = lp[1], l2 = lp[2], l3 = lp[3], l4 = lp[4];

    float s0 = (accA[0] + l4) * SCALE;
    float s1 = (accA[1] + l3) * SCALE;
    float s2 = (accA[2] + l2) * SCALE;
    float s3 = (accA[3] + l1) * SCALE;
    float s4 = (accB[0] + l3) * SCALE;
    float s5 = (accB[1] + l2) * SCALE;
    float s6 = (accB[2] + l1) * SCALE;
    float s7 = (accB[3] + l0) * SCALE;

    // chunk row-max across the 4 lane groups
    float cm = fmaxf(fmaxf(fmaxf(s0, s1), fmaxf(s2, s3)),
                     fmaxf(fmaxf(s4, s5), fmaxf(s6, s7)));
    cm = fmaxf(cm, __shfl_xor(cm, 16, 64));
    cm = fmaxf(cm, __shfl_xor(cm, 32, 64));

    float mn   = fmaxf(m, cm);
    float corr = exp2f((m - mn) * L2E);
    m = mn;

    float p0 = exp2f((s0 - m) * L2E), p1 = exp2f((s1 - m) * L2E);
    float p2 = exp2f((s2 - m) * L2E), p3 = exp2f((s3 - m) * L2E);
    float p4 = exp2f((s4 - m) * L2E), p5 = exp2f((s5 - m) * L2E);
    float p6 = exp2f((s6 - m) * L2E), p7 = exp2f((s7 - m) * L2E);
    lpart = lpart * corr + ((p0 + p1) + (p2 + p3)) + ((p4 + p5) + (p6 + p7));

    accO0[0] *= corr; accO0[1] *= corr; accO0[2] *= corr; accO0[3] *= corr;
    accO1[0] *= corr; accO1[1] *= corr; accO1[2] *= corr; accO1[3] *= corr;

    // P^T B-frag: lane needs keys k = g*8..g*8+7 (bf16 pairs, e ascending)
    int w0 = cvtpk(p0, p1), w1 = cvtpk(p2, p3);
    int w2 = cvtpk(p4, p5), w3 = cvtpk(p6, p7);
    int srcA = ((g & 1) << 5) + qrow;         // group 2*(g&1)
    int srcB = srcA + 16;                     // group 2*(g&1)+1
    int x0 = __shfl(w0, srcA, 64), x1 = __shfl(w1, srcA, 64);
    int x2 = __shfl(w2, srcA, 64), x3 = __shfl(w3, srcA, 64);
    int y0s = __shfl(w0, srcB, 64), y1s = __shfl(w1, srcB, 64);
    int y2s = __shfl(w2, srcB, 64), y3s = __shfl(w3, srcB, 64);
    bool thi = (g >> 1) != 0;                 // which S-tile feeds this group
    union { i32x4 i4; bf16x8 s8; } up;
    up.i4 = (i32x4){ thi ? x2 : x0, thi ? x3 : x1,
                     thi ? y2s : y0s, thi ? y3s : y1s };

    accO0 = __builtin_amdgcn_mfma_f32_16x16x32_bf16(vf0, up.s8, accO0, 0, 0, 0);
    accO1 = __builtin_amdgcn_mfma_f32_16x16x32_bf16(vf1, up.s8, accO1, 0, 0, 0);

    kf0 = nk0; kf1 = nk1; vf0 = nv0; vf1 = nv1;
  }

  // final row-sum of l across groups; normalize and store
  float lsum = lpart + __shfl_xor(lpart, 16, 64);
  lsum += __shfl_xor(lsum, 32, 64);
  float inv = 1.0f / lsum;

  #pragma unroll
  for (int r = 0; r < 4; r++) {
    int d0 = 4 * g + r;
    o_sp[(size_t)(d0 * 4 + head) * 4096 + i]        = accO0[r] * inv;
    o_sp[(size_t)((16 + d0) * 4 + head) * 4096 + i] = accO1[r] * inv;
  }
}

// ---------------------------------------------------------------------------
extern "C" void kernel_launch(void* const* d_in, const int* in_sizes, int n_in,
                              void* d_out, int out_size, void* d_ws, size_t ws_size,
                              hipStream_t stream) {
  (void)in_sizes; (void)n_in; (void)out_size; (void)ws_size;
  const float* x1      = (const float*)d_in[0];
  const float* x2      = (const float*)d_in[1];
  const float* w_ch    = (const float*)d_in[2];
  const float* b_ch    = (const float*)d_in[3];
  const float* gamma_l = (const float*)d_in[4];
  const float* beta_l  = (const float*)d_in[5];
  const float* gamma_h = (const float*)d_in[6];
  const float* beta_h  = (const float*)d_in[7];
  const float* gamma2  = (const float*)d_in[8];
  const float* beta2   = (const float*)d_in[9];
  const float* kv_dw   = (const float*)d_in[10];
  const float* kv_pw   = (const float*)d_in[11];
  const float* q_dw    = (const float*)d_in[12];
  const float* q_pw    = (const float*)d_in[13];
  const float* out_dw  = (const float*)d_in[14];
  const float* out_pw  = (const float*)d_in[15];
  const float* w_mlp   = (const float*)d_in[16];
  const float* rtab    = (const float*)d_in[17];

  float* ws = (float*)d_ws;
  float* x1n  = ws + 0;         // 131072
  float* x2n  = ws + 131072;    // 524288
  float* res8 = ws + 655360;    // 65536
  float* kvdw = ws + 720896;    // 131072
  float* kv8  = ws + 851968;    // 131072
  float* qdw  = ws + 983040;    // 524288
  float* qb   = ws + 1507328;   // 524288
  unsigned short* Kb = (unsigned short*)(ws + 2031616);  // 524288 bf16 (262144 f)
  unsigned short* Vt = (unsigned short*)(ws + 2293760);  // 524288 bf16
  float* r16  = ws + 2555904;   // 524288
  float* o_sp = ws + 3080192;   // 524288
  float* odw  = ws + 3604480;   // 524288
  float* res2 = ws + 4128768;   // 524288
  float* ybuf = ws + 4653056;   // 524288 -> ends 5177344 floats (~20.7 MB)

  bn_kernel<false><<<256, 256, 0, stream>>>(x1, x1n, gamma_l, beta_l, 512);
  bn_kernel<false><<<128, 256, 0, stream>>>(x2, x2n, gamma_h, beta_h, 4096);
  pw2_kernel<2><<<128, 256, 0, stream>>>(x1, w_ch, b_ch, nullptr, res8, 256, 512, 1);
  dw_kernel<<<512, 256, 0, stream>>>(x1n, kv_dw, kvdw, 8, 64, 512);
  pw2_kernel<2><<<256, 256, 0, stream>>>(kvdw, kv_pw, nullptr, nullptr, kv8, 256, 512, 1);
  dw_kernel<<<2048, 256, 0, stream>>>(x2n, q_dw, qdw, 16, 256, 4096);
  pw2_kernel<4><<<512, 256, 0, stream>>>(qdw, q_pw, nullptr, nullptr, qb, 128, 4096, 4);
  interp_res_kernel<<<2048, 256, 0, stream>>>(res8, r16);
  interp_kv_kernel<<<4096, 256, 0, stream>>>(kv8, Kb, Vt);
  attn_mfma_kernel<<<256, 256, 0, stream>>>(qb, Kb, Vt, rtab, o_sp);
  dw_kernel<<<2048, 256, 0, stream>>>(o_sp, out_dw, odw, 16, 256, 4096);
  pw2_kernel<4><<<512, 256, 0, stream>>>(odw, out_pw, nullptr, r16, res2, 128, 4096, 4);
  bn_kernel<true><<<128, 256, 0, stream>>>(res2, ybuf, gamma2, beta2, 4096);
  pw2_kernel<4><<<512, 256, 0, stream>>>(ybuf, w_mlp, nullptr, res2, (float*)d_out, 128, 4096, 4);
}